// Round 2
// baseline (305.763 us; speedup 1.0000x reference)
//
#include <hip/hip_runtime.h>
#include <hip/hip_bf16.h>

// Simple_6270652252303: B=64, L=63 (4032 rows). Only the text branch feeds the
// output (audio/video are dead code). 3 kernels:
//   K1: text -> t2, delta, Bm, Cm (row-parallel, wave per row)
//   K2: S6 selective scan -> y    (wave per 2 (b,d); lanes over N)
//   K3: head y@cW1+cb1 @cW2+cb2 -> out
// Input dtype (f32 per reference vs bf16 harness variant) is detected at
// runtime from tW1's bit patterns; all loads go through templated LD<ISB>.

typedef __hip_bfloat16 bf16;

#define BATCH 64
#define SEQ   63
#define ROWS  (BATCH * SEQ)   // 4032
#define DIN   100
#define H1    128
#define DM    100
#define NS    300

__device__ __forceinline__ float waveReduceSum(float v) {
#pragma unroll
    for (int off = 32; off > 0; off >>= 1) v += __shfl_xor(v, off, 64);
    return v;
}
__device__ __forceinline__ float lrelu(float x) { return x >= 0.f ? x : 0.01f * x; }
__device__ __forceinline__ float softplusf(float x) {
    return (x > 20.f) ? x : log1pf(__expf(x));
}

template<bool ISB>
__device__ __forceinline__ float LD(const void* p, int i) {
    if (ISB) return __bfloat162float(((const bf16*)p)[i]);
    else     return ((const float*)p)[i];
}

// Detect whether float arrays are stored as bf16 (true) or f32 (false).
// Probe = first 128 uint16 words of tW1 (valid in both worlds: >=64 floats).
// bf16 world: all decode to small weights, none exactly-zero-pattern-heavy.
// f32 world: even words are mantissa low-halves -> huge decoded values
// (random bits) OR exactly 0x0000 (if values are bf16-rounded f32s).
__device__ __forceinline__ bool detect_bf16(const unsigned short* __restrict__ probe) {
    __shared__ int s_isb;
    const int t = threadIdx.x;
    if (t < 64) {
        const unsigned u0 = probe[t * 2];
        const unsigned u1 = probe[t * 2 + 1];
        const float v0 = fabsf(__uint_as_float(u0 << 16));
        const float v1 = fabsf(__uint_as_float(u1 << 16));
        const bool big = !(v0 < 1000.f) || !(v1 < 1000.f);  // NaN-safe
        const bool zero_even = (u0 == 0u);
        const unsigned long long mb = __ballot(big);
        const unsigned long long mz = __ballot(zero_even);
        if (t == 0) s_isb = (mb == 0ULL && __popcll(mz) < 32) ? 1 : 0;
    }
    __syncthreads();
    return s_isb != 0;
}

// ---------------------------------------------------------------------------
// K1 body: fused text branch, one wave per row, 4 rows per block.
// ---------------------------------------------------------------------------
template<bool ISB>
__device__ __forceinline__ void text_impl(
    const void* __restrict__ text,
    const void* __restrict__ tW1, const void* __restrict__ tb1,
    const void* __restrict__ tg1, const void* __restrict__ tbe1,
    const void* __restrict__ tW2, const void* __restrict__ tb2,
    const void* __restrict__ tg2, const void* __restrict__ tbe2,
    const void* __restrict__ sW1, const void* __restrict__ sb1,
    const void* __restrict__ sW2, const void* __restrict__ sb2,
    const void* __restrict__ sW3, const void* __restrict__ sb3,
    float* __restrict__ t2o, float* __restrict__ deltao,
    float* __restrict__ Bmo, float* __restrict__ Cmo,
    float (&xbuf)[4][128], float (&t1buf)[4][128], float (&t2buf)[4][128])
{
    const int w    = threadIdx.x >> 6;
    const int lane = threadIdx.x & 63;
    const int row  = blockIdx.x * 4 + w;   // grid 1008 -> rows 0..4031

    // stage x row
    xbuf[w][lane] = LD<ISB>(text, row * DIN + lane);
    if (lane < DIN - 64) xbuf[w][lane + 64] = LD<ISB>(text, row * DIN + lane + 64);
    __syncthreads();

    // GEMM1 (100 -> 128): lane covers j=lane, j=lane+64
    float a0 = LD<ISB>(tb1, lane);
    float a1 = LD<ISB>(tb1, lane + 64);
#pragma unroll 4
    for (int k = 0; k < DIN; ++k) {
        const float xv = xbuf[w][k];
        a0 += xv * LD<ISB>(tW1, k * H1 + lane);
        a1 += xv * LD<ISB>(tW1, k * H1 + lane + 64);
    }
    {   // LN(128) + LReLU
        const float s  = waveReduceSum(a0 + a1);
        const float ss = waveReduceSum(a0 * a0 + a1 * a1);
        const float m  = s * (1.f / 128.f);
        const float rstd = rsqrtf(ss * (1.f / 128.f) - m * m + 1e-5f);
        t1buf[w][lane]      = lrelu((a0 - m) * rstd * LD<ISB>(tg1, lane)      + LD<ISB>(tbe1, lane));
        t1buf[w][lane + 64] = lrelu((a1 - m) * rstd * LD<ISB>(tg1, lane + 64) + LD<ISB>(tbe1, lane + 64));
    }
    __syncthreads();

    // GEMM2 (128 -> 100): lane covers j=lane (always), j=lane+64 if lane<36
    const bool v2 = (lane < DM - 64);
    const int  j2 = v2 ? lane + 64 : 0;
    float c0 = LD<ISB>(tb2, lane);
    float c1 = LD<ISB>(tb2, j2);
#pragma unroll 4
    for (int k = 0; k < H1; ++k) {
        const float tv = t1buf[w][k];
        c0 += tv * LD<ISB>(tW2, k * DM + lane);
        c1 += tv * LD<ISB>(tW2, k * DM + j2);
    }
    {   // LN(100) + LReLU
        const float s  = waveReduceSum(c0 + (v2 ? c1 : 0.f));
        const float ss = waveReduceSum(c0 * c0 + (v2 ? c1 * c1 : 0.f));
        const float m  = s * (1.f / 100.f);
        const float rstd = rsqrtf(ss * (1.f / 100.f) - m * m + 1e-5f);
        const float t20 = lrelu((c0 - m) * rstd * LD<ISB>(tg2, lane) + LD<ISB>(tbe2, lane));
        t2buf[w][lane] = t20;
        t2o[row * DM + lane] = t20;
        if (v2) {
            const float t21 = lrelu((c1 - m) * rstd * LD<ISB>(tg2, j2) + LD<ISB>(tbe2, j2));
            t2buf[w][j2] = t21;
            t2o[row * DM + j2] = t21;
        }
    }
    __syncthreads();

    // delta (100) + Bm (300) + Cm (300), all over k<100
    float d0 = LD<ISB>(sb1, lane);
    float d1 = LD<ISB>(sb1, j2);
    float accB[5], accC[5];
    int   nc[5];
#pragma unroll
    for (int c = 0; c < 5; ++c) {
        const int n = lane + 64 * c;
        nc[c] = (n < NS) ? n : 0;
        accB[c] = LD<ISB>(sb2, nc[c]);
        accC[c] = LD<ISB>(sb3, nc[c]);
    }
#pragma unroll 2
    for (int k = 0; k < DM; ++k) {
        const float tv = t2buf[w][k];
        d0 += tv * LD<ISB>(sW1, k * DM + lane);
        d1 += tv * LD<ISB>(sW1, k * DM + j2);
#pragma unroll
        for (int c = 0; c < 5; ++c) {
            accB[c] += tv * LD<ISB>(sW2, k * NS + nc[c]);
            accC[c] += tv * LD<ISB>(sW3, k * NS + nc[c]);
        }
    }
    deltao[row * DM + lane] = softplusf(d0);
    if (v2) deltao[row * DM + j2] = softplusf(d1);
#pragma unroll
    for (int c = 0; c < 5; ++c) {
        const int n = lane + 64 * c;
        if (n < NS) {
            Bmo[row * NS + n] = accB[c];
            Cmo[row * NS + n] = accC[c];
        }
    }
}

__global__ __launch_bounds__(256) void k_text_branch(
    const void* text,
    const void* tW1, const void* tb1, const void* tg1, const void* tbe1,
    const void* tW2, const void* tb2, const void* tg2, const void* tbe2,
    const void* sW1, const void* sb1, const void* sW2, const void* sb2,
    const void* sW3, const void* sb3,
    float* t2o, float* deltao, float* Bmo, float* Cmo,
    const unsigned short* probe)
{
    __shared__ float xbuf[4][128];
    __shared__ float t1buf[4][128];
    __shared__ float t2buf[4][128];
    const bool isb = detect_bf16(probe);
    if (isb) text_impl<true >(text, tW1, tb1, tg1, tbe1, tW2, tb2, tg2, tbe2,
                              sW1, sb1, sW2, sb2, sW3, sb3, t2o, deltao, Bmo, Cmo,
                              xbuf, t1buf, t2buf);
    else     text_impl<false>(text, tW1, tb1, tg1, tbe1, tW2, tb2, tg2, tbe2,
                              sW1, sb1, sW2, sb2, sW3, sb3, t2o, deltao, Bmo, Cmo,
                              xbuf, t1buf, t2buf);
}

// ---------------------------------------------------------------------------
// K2: S6 scan. Wave handles 2 d's of one batch; lanes cover N (5 each).
// ---------------------------------------------------------------------------
template<bool ISB>
__device__ __forceinline__ void scan_impl(
    const float* __restrict__ t2, const float* __restrict__ delta,
    const float* __restrict__ Bm, const float* __restrict__ Cm,
    const void* __restrict__ sA, float* __restrict__ y,
    float (&sB)[320], float (&sC)[320])
{
    const int b    = blockIdx.y;
    const int dg   = blockIdx.x;
    const int w    = threadIdx.x >> 6;
    const int lane = threadIdx.x & 63;
    const int d0 = dg * 8 + w * 2;
    const int d1 = d0 + 1;
    const bool v0 = d0 < DM, v1 = d1 < DM;
    const int dc0 = v0 ? d0 : 0, dc1 = v1 ? d1 : 0;

    float A0[5], A1[5], h0[5], h1[5];
#pragma unroll
    for (int c = 0; c < 5; ++c) {
        const int n = lane + 64 * c;
        A0[c] = (n < NS) ? LD<ISB>(sA, dc0 * NS + n) : 0.f;
        A1[c] = (n < NS) ? LD<ISB>(sA, dc1 * NS + n) : 0.f;
        h0[c] = 0.f; h1[c] = 0.f;
    }

    for (int l = 0; l < SEQ; ++l) {
        const int row = b * SEQ + l;
        for (int i = threadIdx.x; i < 320; i += 256) {
            sB[i] = (i < NS) ? Bm[row * NS + i] : 0.f;
            sC[i] = (i < NS) ? Cm[row * NS + i] : 0.f;
        }
        __syncthreads();

        const float de0 = delta[row * DM + dc0];
        const float de1 = delta[row * DM + dc1];
        const float dx0 = v0 ? de0 * t2[row * DM + dc0] : 0.f;
        const float dx1 = v1 ? de1 * t2[row * DM + dc1] : 0.f;

        float acc0 = 0.f, acc1 = 0.f;
#pragma unroll
        for (int c = 0; c < 5; ++c) {
            const int n = lane + 64 * c;
            const float bv = sB[n], cv = sC[n];
            h0[c] = __expf(de0 * A0[c]) * h0[c] + dx0 * bv;
            acc0 += cv * h0[c];
            h1[c] = __expf(de1 * A1[c]) * h1[c] + dx1 * bv;
            acc1 += cv * h1[c];
        }
        acc0 = waveReduceSum(acc0);
        acc1 = waveReduceSum(acc1);
        if (lane == 0) {
            if (v0) y[row * DM + d0] = acc0;
            if (v1) y[row * DM + d1] = acc1;
        }
        __syncthreads();
    }
}

__global__ __launch_bounds__(256) void k_scan(
    const float* t2, const float* delta, const float* Bm, const float* Cm,
    const void* sA, float* y, const unsigned short* probe)
{
    __shared__ float sB[320];
    __shared__ float sC[320];
    const bool isb = detect_bf16(probe);
    if (isb) scan_impl<true >(t2, delta, Bm, Cm, sA, y, sB, sC);
    else     scan_impl<false>(t2, delta, Bm, Cm, sA, y, sB, sC);
}

// ---------------------------------------------------------------------------
// K3: head. Wave per row.
// ---------------------------------------------------------------------------
template<bool ISB>
__device__ __forceinline__ void head_impl(
    const float* __restrict__ y,
    const void* __restrict__ cW1, const void* __restrict__ cb1,
    const void* __restrict__ cW2, const void* __restrict__ cb2,
    void* __restrict__ outp, float (&ybuf)[4][100])
{
    const int w    = threadIdx.x >> 6;
    const int lane = threadIdx.x & 63;
    const int row  = blockIdx.x * 4 + w;

    ybuf[w][lane] = y[row * DM + lane];
    if (lane < DM - 64) ybuf[w][lane + 64] = y[row * DM + lane + 64];
    __syncthreads();

    const bool vi = lane < 50;
    const int  i  = vi ? lane : 0;
    float o1 = LD<ISB>(cb1, i);
#pragma unroll 4
    for (int k = 0; k < DM; ++k) o1 += ybuf[w][k] * LD<ISB>(cW1, k * 50 + i);

    float p0 = vi ? o1 * LD<ISB>(cW2, i * 2 + 0) : 0.f;
    float p1 = vi ? o1 * LD<ISB>(cW2, i * 2 + 1) : 0.f;
    p0 = waveReduceSum(p0);
    p1 = waveReduceSum(p1);
    if (lane == 0) {
        const float r0 = p0 + LD<ISB>(cb2, 0);
        const float r1 = p1 + LD<ISB>(cb2, 1);
        if (ISB) {
            ((bf16*)outp)[row * 2 + 0] = __float2bfloat16(r0);
            ((bf16*)outp)[row * 2 + 1] = __float2bfloat16(r1);
        } else {
            ((float*)outp)[row * 2 + 0] = r0;
            ((float*)outp)[row * 2 + 1] = r1;
        }
    }
}

__global__ __launch_bounds__(256) void k_head(
    const float* y, const void* cW1, const void* cb1,
    const void* cW2, const void* cb2, void* outp, const unsigned short* probe)
{
    __shared__ float ybuf[4][100];
    const bool isb = detect_bf16(probe);
    if (isb) head_impl<true >(y, cW1, cb1, cW2, cb2, outp, ybuf);
    else     head_impl<false>(y, cW1, cb1, cW2, cb2, outp, ybuf);
}

// ---------------------------------------------------------------------------
extern "C" void kernel_launch(void* const* d_in, const int* in_sizes, int n_in,
                              void* d_out, int out_size, void* d_ws, size_t ws_size,
                              hipStream_t stream)
{
    const void* text = d_in[0];
    const void* tW1  = d_in[3];
    const void* tb1  = d_in[4];
    const void* tg1  = d_in[5];
    const void* tbe1 = d_in[6];
    const void* tW2  = d_in[7];
    const void* tb2  = d_in[8];
    const void* tg2  = d_in[9];
    const void* tbe2 = d_in[10];
    const void* sW1  = d_in[11];
    const void* sb1  = d_in[12];
    const void* sW2  = d_in[13];
    const void* sb2  = d_in[14];
    const void* sW3  = d_in[15];
    const void* sb3  = d_in[16];
    const void* sA   = d_in[17];
    const void* cW1  = d_in[34];
    const void* cb1  = d_in[35];
    const void* cW2  = d_in[36];
    const void* cb2  = d_in[37];
    const unsigned short* probe = (const unsigned short*)d_in[3];  // tW1 bits

    float* ws   = (float*)d_ws;
    float* t2v  = ws;                       // ROWS*DM
    float* dev  = t2v + ROWS * DM;          // ROWS*DM
    float* Bmv  = dev + ROWS * DM;          // ROWS*NS
    float* Cmv  = Bmv + ROWS * NS;          // ROWS*NS
    float* yv   = Cmv + ROWS * NS;          // ROWS*DM  (total 14.52 MB)

    k_text_branch<<<ROWS / 4, 256, 0, stream>>>(
        text, tW1, tb1, tg1, tbe1, tW2, tb2, tg2, tbe2,
        sW1, sb1, sW2, sb2, sW3, sb3, t2v, dev, Bmv, Cmv, probe);

    k_scan<<<dim3(13, BATCH), 256, 0, stream>>>(t2v, dev, Bmv, Cmv, sA, yv, probe);

    k_head<<<ROWS / 4, 256, 0, stream>>>(yv, cW1, cb1, cW2, cb2, d_out, probe);
}

// Round 4
// 258.950 us; speedup vs baseline: 1.1808x; 1.1808x over previous
//
#include <hip/hip_runtime.h>
#include <hip/hip_bf16.h>

// Simple_6270652252303. Evidence so far: R2 (dtype detector) PASSED absmax 0.25,
// R3 (bf16 hard-coded) NaN => inputs are float32 (as the reference declares);
// detector is kept as insurance and picks the path per-launch.
// Only the text branch feeds the output (audio/video dead code).
//   K1 k_text: text -> {delta, delta*x} interleaved, Bm, Cm
//              (2 rows per wave, paired loads: each weight pair -> 4 FMAs)
//   K2 k_scan: S6 scan -> y (wave per 2 d's, lanes over N; no LDS, no barriers,
//              register double-buffered prefetch of next step's B/C/ddx)
//   K3 k_head: y @ cW1 + cb1 @ cW2 + cb2 -> out

typedef __hip_bfloat16 bf16;

#define BATCH 64
#define SEQ   63
#define ROWS  (BATCH * SEQ)   // 4032
#define DIN   100
#define H1    128
#define DM    100
#define NS    300

__device__ __forceinline__ float2 up2(unsigned u) {
    float2 r;
    r.x = __uint_as_float(u << 16);
    r.y = __uint_as_float(u & 0xffff0000u);
    return r;
}
template<bool ISB>
__device__ __forceinline__ float LD(const void* p, int i) {
    if (ISB) return __bfloat162float(((const bf16*)p)[i]);
    else     return ((const float*)p)[i];
}
// load pair (elements 2i, 2i+1) as float2
template<bool ISB>
__device__ __forceinline__ float2 LD2(const void* p, int i) {
    if (ISB) return up2(((const unsigned*)p)[i]);
    else     return ((const float2*)p)[i];
}
__device__ __forceinline__ float waveReduceSum(float v) {
#pragma unroll
    for (int off = 32; off > 0; off >>= 1) v += __shfl_xor(v, off, 64);
    return v;
}
__device__ __forceinline__ float lrelu(float x) { return x >= 0.f ? x : 0.01f * x; }
__device__ __forceinline__ float softplusf(float x) {
    return (x > 20.f) ? x : log1pf(__expf(x));
}

// Detect bf16 (true) vs f32 (false) storage from tW1's first 128 u16 words.
// f32 world: low mantissa half-words decode (as bf16) to random huge values.
__device__ __forceinline__ bool detect_bf16(const unsigned short* __restrict__ probe) {
    __shared__ int s_isb;
    const int t = threadIdx.x;
    if (t < 64) {
        const unsigned u0 = probe[t * 2];
        const unsigned u1 = probe[t * 2 + 1];
        const float v0 = fabsf(__uint_as_float(u0 << 16));
        const float v1 = fabsf(__uint_as_float(u1 << 16));
        const bool big = !(v0 < 1000.f) || !(v1 < 1000.f);  // NaN-safe
        const bool zero_even = (u0 == 0u);
        const unsigned long long mb = __ballot(big);
        const unsigned long long mz = __ballot(zero_even);
        if (t == 0) s_isb = (mb == 0ULL && __popcll(mz) < 32) ? 1 : 0;
    }
    __syncthreads();
    return s_isb != 0;
}

// ---------------------------------------------------------------------------
// K1: fused text branch. 2 rows per wave, 4 waves/block -> 8 rows/block.
// ---------------------------------------------------------------------------
template<bool ISB>
__device__ __forceinline__ void text_impl(
    const void* __restrict__ text,
    const void* __restrict__ tW1, const void* __restrict__ tb1,
    const void* __restrict__ tg1, const void* __restrict__ tbe1,
    const void* __restrict__ tW2, const void* __restrict__ tb2,
    const void* __restrict__ tg2, const void* __restrict__ tbe2,
    const void* __restrict__ sW1, const void* __restrict__ sb1,
    const void* __restrict__ sW2, const void* __restrict__ sb2,
    const void* __restrict__ sW3, const void* __restrict__ sb3,
    float* __restrict__ ddx, float* __restrict__ Bmo, float* __restrict__ Cmo,
    float (&xb)[8][100], float (&t1b)[8][128], float (&t2b)[8][100])
{
    const int w    = threadIdx.x >> 6;
    const int lane = threadIdx.x & 63;
    const int r0   = blockIdx.x * 8 + w * 2;   // rows r0, r0+1
    const int s0   = w * 2, s1 = s0 + 1;

    if (lane < 50) {
        const float2 x0 = LD2<ISB>(text, r0 * 50 + lane);
        const float2 x1 = LD2<ISB>(text, (r0 + 1) * 50 + lane);
        xb[s0][2 * lane] = x0.x; xb[s0][2 * lane + 1] = x0.y;
        xb[s1][2 * lane] = x1.x; xb[s1][2 * lane + 1] = x1.y;
    }
    __syncthreads();

    // ---- GEMM1 (100 -> 128): lane covers cols 2*lane, 2*lane+1, both rows ----
    const float2 b1v = LD2<ISB>(tb1, lane);
    float a0x = b1v.x, a0y = b1v.y, a1x = b1v.x, a1y = b1v.y;
#pragma unroll 4
    for (int k = 0; k < DIN; ++k) {
        const float2 wv = LD2<ISB>(tW1, k * 64 + lane);
        const float x0 = xb[s0][k], x1 = xb[s1][k];
        a0x += x0 * wv.x; a0y += x0 * wv.y;
        a1x += x1 * wv.x; a1y += x1 * wv.y;
    }
    {   // LN(128)+LReLU per row
        const float2 g = LD2<ISB>(tg1, lane), be = LD2<ISB>(tbe1, lane);
        const float sm0 = waveReduceSum(a0x + a0y);
        const float sq0 = waveReduceSum(a0x * a0x + a0y * a0y);
        const float sm1 = waveReduceSum(a1x + a1y);
        const float sq1 = waveReduceSum(a1x * a1x + a1y * a1y);
        const float m0 = sm0 * (1.f / 128.f), m1 = sm1 * (1.f / 128.f);
        const float rs0 = rsqrtf(sq0 * (1.f / 128.f) - m0 * m0 + 1e-5f);
        const float rs1 = rsqrtf(sq1 * (1.f / 128.f) - m1 * m1 + 1e-5f);
        t1b[s0][2 * lane]     = lrelu((a0x - m0) * rs0 * g.x + be.x);
        t1b[s0][2 * lane + 1] = lrelu((a0y - m0) * rs0 * g.y + be.y);
        t1b[s1][2 * lane]     = lrelu((a1x - m1) * rs1 * g.x + be.x);
        t1b[s1][2 * lane + 1] = lrelu((a1y - m1) * rs1 * g.y + be.y);
    }
    __syncthreads();

    // ---- GEMM2 (128 -> 100): lanes 0..49 cover cols 2li, 2li+1 ----
    const bool act = lane < 50;
    const int  li  = act ? lane : 0;
    const float2 b2v = LD2<ISB>(tb2, li);
    float c0x = b2v.x, c0y = b2v.y, c1x = b2v.x, c1y = b2v.y;
#pragma unroll 4
    for (int k = 0; k < H1; ++k) {
        const float2 wv = LD2<ISB>(tW2, k * 50 + li);
        const float t0 = t1b[s0][k], t1 = t1b[s1][k];
        c0x += t0 * wv.x; c0y += t0 * wv.y;
        c1x += t1 * wv.x; c1y += t1 * wv.y;
    }
    {   // LN(100)+LReLU per row
        const float sm0 = waveReduceSum(act ? c0x + c0y : 0.f);
        const float sq0 = waveReduceSum(act ? c0x * c0x + c0y * c0y : 0.f);
        const float sm1 = waveReduceSum(act ? c1x + c1y : 0.f);
        const float sq1 = waveReduceSum(act ? c1x * c1x + c1y * c1y : 0.f);
        const float m0 = sm0 * 0.01f, m1 = sm1 * 0.01f;
        const float rs0 = rsqrtf(sq0 * 0.01f - m0 * m0 + 1e-5f);
        const float rs1 = rsqrtf(sq1 * 0.01f - m1 * m1 + 1e-5f);
        if (act) {
            const float2 g = LD2<ISB>(tg2, lane), be = LD2<ISB>(tbe2, lane);
            t2b[s0][2 * lane]     = lrelu((c0x - m0) * rs0 * g.x + be.x);
            t2b[s0][2 * lane + 1] = lrelu((c0y - m0) * rs0 * g.y + be.y);
            t2b[s1][2 * lane]     = lrelu((c1x - m1) * rs1 * g.x + be.x);
            t2b[s1][2 * lane + 1] = lrelu((c1y - m1) * rs1 * g.y + be.y);
        }
    }
    __syncthreads();

    // ---- fused delta(100) + Bm(300) + Cm(300) over k<100, both rows ----
    const float2 sbv = LD2<ISB>(sb1, li);
    float dl0x = sbv.x, dl0y = sbv.y, dl1x = sbv.x, dl1y = sbv.y;
    int pc[3]; bool pv[3];
    float2 aB0[3], aB1[3], aC0[3], aC1[3];
#pragma unroll
    for (int cc = 0; cc < 3; ++cc) {
        const int p = lane + 64 * cc;
        pv[cc] = p < 150;
        pc[cc] = pv[cc] ? p : 0;
        const float2 bb = LD2<ISB>(sb2, pc[cc]);
        const float2 cb = LD2<ISB>(sb3, pc[cc]);
        aB0[cc] = bb; aB1[cc] = bb;
        aC0[cc] = cb; aC1[cc] = cb;
    }
#pragma unroll 2
    for (int k = 0; k < DM; ++k) {
        const float t0 = t2b[s0][k], t1 = t2b[s1][k];
        const float2 wv = LD2<ISB>(sW1, k * 50 + li);
        dl0x += t0 * wv.x; dl0y += t0 * wv.y;
        dl1x += t1 * wv.x; dl1y += t1 * wv.y;
#pragma unroll
        for (int cc = 0; cc < 3; ++cc) {
            const float2 bw = LD2<ISB>(sW2, k * 150 + pc[cc]);
            const float2 cw = LD2<ISB>(sW3, k * 150 + pc[cc]);
            aB0[cc].x += t0 * bw.x; aB0[cc].y += t0 * bw.y;
            aB1[cc].x += t1 * bw.x; aB1[cc].y += t1 * bw.y;
            aC0[cc].x += t0 * cw.x; aC0[cc].y += t0 * cw.y;
            aC1[cc].x += t1 * cw.x; aC1[cc].y += t1 * cw.y;
        }
    }
    if (act) {
        float4 o;
        float de = softplusf(dl0x);
        o.x = de; o.y = de * t2b[s0][2 * lane];
        de = softplusf(dl0y);
        o.z = de; o.w = de * t2b[s0][2 * lane + 1];
        *(float4*)(ddx + r0 * (2 * DM) + 4 * lane) = o;
        de = softplusf(dl1x);
        o.x = de; o.y = de * t2b[s1][2 * lane];
        de = softplusf(dl1y);
        o.z = de; o.w = de * t2b[s1][2 * lane + 1];
        *(float4*)(ddx + (r0 + 1) * (2 * DM) + 4 * lane) = o;
    }
#pragma unroll
    for (int cc = 0; cc < 3; ++cc) {
        if (pv[cc]) {
            *(float2*)(Bmo + r0 * NS + 2 * pc[cc])       = aB0[cc];
            *(float2*)(Bmo + (r0 + 1) * NS + 2 * pc[cc]) = aB1[cc];
            *(float2*)(Cmo + r0 * NS + 2 * pc[cc])       = aC0[cc];
            *(float2*)(Cmo + (r0 + 1) * NS + 2 * pc[cc]) = aC1[cc];
        }
    }
}

__global__ __launch_bounds__(256) void k_text(
    const void* text,
    const void* tW1, const void* tb1, const void* tg1, const void* tbe1,
    const void* tW2, const void* tb2, const void* tg2, const void* tbe2,
    const void* sW1, const void* sb1, const void* sW2, const void* sb2,
    const void* sW3, const void* sb3,
    float* ddx, float* Bmo, float* Cmo, const unsigned short* probe)
{
    __shared__ float xb[8][100];
    __shared__ float t1b[8][128];
    __shared__ float t2b[8][100];
    if (detect_bf16(probe))
        text_impl<true >(text, tW1, tb1, tg1, tbe1, tW2, tb2, tg2, tbe2,
                         sW1, sb1, sW2, sb2, sW3, sb3, ddx, Bmo, Cmo, xb, t1b, t2b);
    else
        text_impl<false>(text, tW1, tb1, tg1, tbe1, tW2, tb2, tg2, tbe2,
                         sW1, sb1, sW2, sb2, sW3, sb3, ddx, Bmo, Cmo, xb, t1b, t2b);
}

// ---------------------------------------------------------------------------
// K2: S6 scan. Wave wid: batch b=wid/50, d-pair dp=wid%50 (d0=2dp, d1=2dp+1).
// Lanes cover N (5 states/lane). No LDS/barriers; next step prefetched.
// ---------------------------------------------------------------------------
template<bool ISB>
__device__ __forceinline__ void scan_impl(
    const float* __restrict__ ddx, const float* __restrict__ Bm,
    const float* __restrict__ Cm, const void* __restrict__ sA,
    float* __restrict__ y)
{
    const int w    = threadIdx.x >> 6;
    const int lane = threadIdx.x & 63;
    const int wid  = blockIdx.x * 4 + w;      // 0..3199
    const int b    = wid / 50;
    const int dp   = wid % 50;
    const int d0   = 2 * dp, d1 = d0 + 1;

    int nc[5]; bool nv[5];
    float A0[5], A1[5], h0[5], h1[5];
#pragma unroll
    for (int c = 0; c < 5; ++c) {
        const int n = lane + 64 * c;
        nv[c] = n < NS;
        nc[c] = nv[c] ? n : 0;
        A0[c] = nv[c] ? LD<ISB>(sA, d0 * NS + nc[c]) : 0.f;
        A1[c] = nv[c] ? LD<ISB>(sA, d1 * NS + nc[c]) : 0.f;
        h0[c] = 0.f; h1[c] = 0.f;
    }

    const float* dd_p = ddx + (b * SEQ) * (2 * DM) + 4 * dp;  // {de0,dx0,de1,dx1}
    const float* Bp   = Bm  + (b * SEQ) * NS;
    const float* Cp   = Cm  + (b * SEQ) * NS;
    float*       yp   = y   + (b * SEQ) * DM + d0;

    float4 dd = *(const float4*)dd_p;
    float bv[5], cv[5], nbv[5], ncv[5];
#pragma unroll
    for (int c = 0; c < 5; ++c) {
        bv[c] = nv[c] ? Bp[nc[c]] : 0.f;
        cv[c] = nv[c] ? Cp[nc[c]] : 0.f;
    }

    for (int l = 0; l < SEQ; ++l) {
        float4 ndd = dd;
        if (l + 1 < SEQ) {
            ndd = *(const float4*)(dd_p + (l + 1) * (2 * DM));
#pragma unroll
            for (int c = 0; c < 5; ++c) {
                nbv[c] = nv[c] ? Bp[(l + 1) * NS + nc[c]] : 0.f;
                ncv[c] = nv[c] ? Cp[(l + 1) * NS + nc[c]] : 0.f;
            }
        }
        float acc0 = 0.f, acc1 = 0.f;
#pragma unroll
        for (int c = 0; c < 5; ++c) {
            h0[c] = __expf(dd.x * A0[c]) * h0[c] + dd.y * bv[c];
            acc0 += cv[c] * h0[c];
            h1[c] = __expf(dd.z * A1[c]) * h1[c] + dd.w * bv[c];
            acc1 += cv[c] * h1[c];
        }
        acc0 = waveReduceSum(acc0);
        acc1 = waveReduceSum(acc1);
        if (lane == 0) *(float2*)(yp + l * DM) = make_float2(acc0, acc1);
        dd = ndd;
#pragma unroll
        for (int c = 0; c < 5; ++c) { bv[c] = nbv[c]; cv[c] = ncv[c]; }
    }
}

__global__ __launch_bounds__(256) void k_scan(
    const float* ddx, const float* Bm, const float* Cm,
    const void* sA, float* y, const unsigned short* probe)
{
    if (detect_bf16(probe)) scan_impl<true >(ddx, Bm, Cm, sA, y);
    else                    scan_impl<false>(ddx, Bm, Cm, sA, y);
}

// ---------------------------------------------------------------------------
// K3: head. Wave per row.
// ---------------------------------------------------------------------------
template<bool ISB>
__device__ __forceinline__ void head_impl(
    const float* __restrict__ y,
    const void* __restrict__ cW1, const void* __restrict__ cb1,
    const void* __restrict__ cW2, const void* __restrict__ cb2,
    void* __restrict__ outp, float (&ybuf)[4][100])
{
    const int w    = threadIdx.x >> 6;
    const int lane = threadIdx.x & 63;
    const int row  = blockIdx.x * 4 + w;

    ybuf[w][lane] = y[row * DM + lane];
    if (lane < DM - 64) ybuf[w][lane + 64] = y[row * DM + lane + 64];
    __syncthreads();

    const bool vi = lane < 50;
    const int  i  = vi ? lane : 0;
    float o1 = LD<ISB>(cb1, i);
#pragma unroll 4
    for (int k = 0; k < DM; ++k) o1 += ybuf[w][k] * LD<ISB>(cW1, k * 50 + i);

    float p0 = vi ? o1 * LD<ISB>(cW2, i * 2 + 0) : 0.f;
    float p1 = vi ? o1 * LD<ISB>(cW2, i * 2 + 1) : 0.f;
    p0 = waveReduceSum(p0);
    p1 = waveReduceSum(p1);
    if (lane == 0) {
        const float r0 = p0 + LD<ISB>(cb2, 0);
        const float r1 = p1 + LD<ISB>(cb2, 1);
        if (ISB) {
            ((bf16*)outp)[row * 2 + 0] = __float2bfloat16(r0);
            ((bf16*)outp)[row * 2 + 1] = __float2bfloat16(r1);
        } else {
            *(float2*)((float*)outp + row * 2) = make_float2(r0, r1);
        }
    }
}

__global__ __launch_bounds__(256) void k_head(
    const float* y, const void* cW1, const void* cb1,
    const void* cW2, const void* cb2, void* outp, const unsigned short* probe)
{
    __shared__ float ybuf[4][100];
    if (detect_bf16(probe)) head_impl<true >(y, cW1, cb1, cW2, cb2, outp, ybuf);
    else                    head_impl<false>(y, cW1, cb1, cW2, cb2, outp, ybuf);
}

// ---------------------------------------------------------------------------
extern "C" void kernel_launch(void* const* d_in, const int* in_sizes, int n_in,
                              void* d_out, int out_size, void* d_ws, size_t ws_size,
                              hipStream_t stream)
{
    const void* text = d_in[0];
    const void* tW1  = d_in[3];
    const void* tb1  = d_in[4];
    const void* tg1  = d_in[5];
    const void* tbe1 = d_in[6];
    const void* tW2  = d_in[7];
    const void* tb2  = d_in[8];
    const void* tg2  = d_in[9];
    const void* tbe2 = d_in[10];
    const void* sW1  = d_in[11];
    const void* sb1  = d_in[12];
    const void* sW2  = d_in[13];
    const void* sb2  = d_in[14];
    const void* sW3  = d_in[15];
    const void* sb3  = d_in[16];
    const void* sA   = d_in[17];
    const void* cW1  = d_in[34];
    const void* cb1  = d_in[35];
    const void* cW2  = d_in[36];
    const void* cb2  = d_in[37];
    const unsigned short* probe = (const unsigned short*)d_in[3];

    float* ws  = (float*)d_ws;
    float* ddx = ws;                          // ROWS * 200  ({delta, delta*x})
    float* Bmv = ddx + ROWS * 2 * DM;         // ROWS * 300
    float* Cmv = Bmv + ROWS * NS;             // ROWS * 300
    float* yv  = Cmv + ROWS * NS;             // ROWS * 100   (~14.5 MB total)

    k_text<<<ROWS / 8, 256, 0, stream>>>(
        text, tW1, tb1, tg1, tbe1, tW2, tb2, tg2, tbe2,
        sW1, sb1, sW2, sb2, sW3, sb3, ddx, Bmv, Cmv, probe);

    k_scan<<<3200 / 4, 256, 0, stream>>>(ddx, Bmv, Cmv, sA, yv, probe);

    k_head<<<ROWS / 4, 256, 0, stream>>>(yv, cW1, cb1, cW2, cb2, d_out, probe);
}